// Round 4
// baseline (4542.159 us; speedup 1.0000x reference)
//
#include <hip/hip_runtime.h>
#include <hip/hip_bf16.h>
#include <math.h>

#define N_PTS 131072
#define NSEG  8192
#define NKK   20
#define PRED  12
#define KP    192   // padded K: 2 rel + 40 dtp + 128 h + 22 zero

typedef __hip_bfloat16 bf16;
typedef __attribute__((ext_vector_type(8))) short short8;
typedef __attribute__((ext_vector_type(4))) float float4v;

__device__ __forceinline__ float b2f(bf16 x){ return __bfloat162float(x); }
__device__ __forceinline__ float sigm(float x){ return 1.0f/(1.0f+__expf(-x)); }
__device__ __forceinline__ float tanh_f(float x){
  x = fminf(15.f, fmaxf(-15.f, x));
  float e = __expf(2.f*x);
  return (e-1.f)/(e+1.f);
}
__device__ __forceinline__ float ldf(const void* p, long long i, bool bf){
  return bf ? __bfloat162float(((const bf16*)p)[i]) : ((const float*)p)[i];
}
__device__ __forceinline__ int ldseg(const void* p, long long i, bool i64){
  return i64 ? (int)(((const long long*)p)[i]) : ((const int*)p)[i];
}
__device__ __forceinline__ void stf(void* p, long long i, float v, bool bf){
  if(bf) ((bf16*)p)[i] = __float2bfloat16(v);
  else   ((float*)p)[i] = v;
}

// ---------- dtype probes: flags[0]=float-is-bf16, flags[1]=segids-int64, flags[2]=mask mode(0=i32,1=byte,2=i64)
__global__ void k_probe(const unsigned short* __restrict__ wx,
                        const int* __restrict__ seg,
                        const unsigned char* __restrict__ msk,
                        int* __restrict__ flags){
  int lane = threadIdx.x & 63;
  unsigned short h1 = wx[2*lane], h2 = wx[128+2*lane];
  int e1 = (h1>>7)&255, e2 = (h2>>7)&255;
  bool p1 = (e1>=100 && e1<=132), p2 = (e2>=100 && e2<=132);
  int cnt = __popcll(__ballot(p1)) + __popcll(__ballot(p2));
  int v = seg[65536+lane];
  int zc = __popcll(__ballot((lane&1) && v==0));
  bool nz1=false, nz2=false;
  for(int i=lane;i<4096;i+=64){
    unsigned char b = msk[i];
    if((i&3)!=0 && b) nz1=true;
    if((i&7)==4 && b) nz2=true;
  }
  unsigned long long b1 = __ballot(nz1), b2 = __ballot(nz2);
  if(lane==0){
    flags[0] = (cnt>=64) ? 1 : 0;
    flags[1] = (zc>=24) ? 1 : 0;
    flags[2] = b1 ? 1 : (b2 ? 0 : 2);
  }
}

__global__ void k_conv(const unsigned char* __restrict__ mraw, const int* __restrict__ flags,
                       unsigned char* __restrict__ mask){
  int i = blockIdx.x*256+threadIdx.x;
  if(i>=N_PTS) return;
  int mode = flags[2];
  unsigned char v;
  if(mode==1)      v = mraw[i]!=0;
  else if(mode==0) v = ((const int*)mraw)[i]!=0;
  else             v = ((const long long*)mraw)[i]!=0;
  mask[i]=v;
}

__global__ void k_segstart(const void* __restrict__ seg, const int* __restrict__ flags,
                           int* __restrict__ start){
  int s = blockIdx.x*256+threadIdx.x;
  if(s>NSEG) return;
  bool i64 = flags[1]!=0;
  int lo=0, hi=N_PTS;
  while(lo<hi){ int mid=(lo+hi)>>1; if(ldseg(seg,mid,i64)<s) lo=mid+1; else hi=mid; }
  start[s]=lo;
}

// ---------- fold weights into wT[512][192] bf16 (n-major, k-contiguous, B-operand layout) + bias_eff fp32[512]
__global__ void k_fold(const void* __restrict__ Wpos, const void* __restrict__ bpos,
                       const void* __restrict__ Wfld, const void* __restrict__ bfld,
                       const void* __restrict__ Wx,   const void* __restrict__ Wh,
                       const void* __restrict__ blstm, const int* __restrict__ flags,
                       short* __restrict__ wT, float* __restrict__ bias){
  int idx = blockIdx.x*256+threadIdx.x;
  bool bf = flags[0]!=0;
  if(idx < 512*KP){
    int n = idx/KP, k = idx - n*KP;
    float v;
    if(k<2){
      float a=0; for(int j=0;j<64;j++) a += ldf(Wpos,k*64+j,bf)*ldf(Wx,j*512+n,bf);
      v=a;
    } else if(k<42){
      int kk=k-2; float a=0; for(int j=0;j<64;j++) a += ldf(Wfld,kk*64+j,bf)*ldf(Wx,(64+j)*512+n,bf);
      v=a;
    } else if(k<170){
      v = ldf(Wh,(long long)(k-42)*512+n,bf);
    } else v = 0.f;
    ((bf16*)wT)[(long long)n*KP+k] = __float2bfloat16(v);
  } else if(idx < 512*KP+512){
    int c = idx - 512*KP;
    float a=ldf(blstm,c,bf);
    for(int j=0;j<64;j++) a += ldf(bpos,j,bf)*ldf(Wx,j*512+c,bf) + ldf(bfld,j,bf)*ldf(Wx,(64+j)*512+c,bf);
    bias[c]=a;
  }
}

// ---------- init: build Apk[p][192], c=0, rel/pos fp32, al fp32, traj[0] ----------
__global__ void k_init(const void* __restrict__ sf, const void* __restrict__ lastpos,
                       const void* __restrict__ alpha0, const void* __restrict__ fd0,
                       const void* __restrict__ Wout, const void* __restrict__ bout,
                       const int* __restrict__ flags,
                       short* __restrict__ Apk, float* __restrict__ c,
                       float* __restrict__ rel, float* __restrict__ pos,
                       float* __restrict__ al, void* __restrict__ traj){
  int grp = threadIdx.x>>6, lane = threadIdx.x&63;
  int p = blockIdx.x*4+grp;
  bool bf = flags[0]!=0;
  bf16* Ap = (bf16*)Apk + (long long)p*KP;
  float h0 = ldf(sf,(long long)p*128+lane,bf);
  float h1 = ldf(sf,(long long)p*128+64+lane,bf);
  Ap[42+lane]      = __float2bfloat16(h0);
  Ap[42+64+lane]   = __float2bfloat16(h1);
  c[(long long)p*128+lane]=0.f; c[(long long)p*128+64+lane]=0.f;
  float o0 = h0*ldf(Wout,lane*2,bf)   + h1*ldf(Wout,(64+lane)*2,bf);
  float o1 = h0*ldf(Wout,lane*2+1,bf) + h1*ldf(Wout,(64+lane)*2+1,bf);
  for(int m=1;m<64;m<<=1){ o0 += __shfl_xor(o0,m); o1 += __shfl_xor(o1,m); }
  o0 += ldf(bout,0,bf); o1 += ldf(bout,1,bf);
  float a = 0.f;
  if(lane<NKK) a = ldf(alpha0,(long long)p*NKK+lane,bf);
  float s = a;
  for(int m=1;m<64;m<<=1) s += __shfl_xor(s,m);
  float aln = a/s;
  if(lane<NKK) al[(long long)p*NKK+lane] = aln;
  float alq = __shfl(aln, lane>>1);
  if(lane<2*NKK) Ap[2+lane] = __float2bfloat16(ldf(fd0,(long long)p*2*NKK+lane,bf)*alq);
  if(lane<22)    Ap[170+lane] = __float2bfloat16(0.f);
  if(lane==0){
    Ap[0]=__float2bfloat16(o0); Ap[1]=__float2bfloat16(o1);
    rel[p*2]=o0; rel[p*2+1]=o1;
    pos[p*2]   = ldf(lastpos,p*2,bf)  +o0;
    pos[p*2+1] = ldf(lastpos,p*2+1,bf)+o1;
    stf(traj, (long long)p*2,   o0, bf);
    stf(traj, (long long)p*2+1, o1, bf);
  }
}

// ---------- per-step: segment max over h (bf16 in Apk) ----------
__global__ void s1a_segmax(const short* __restrict__ Apk, const int* __restrict__ start,
                           float* __restrict__ segmax){
  int s = blockIdx.x;
  int d = threadIdx.x;
  int a = start[s], b = start[s+1];
  float m = -INFINITY;
  for(int i=a;i<b;i++) m = fmaxf(m, b2f(((const bf16*)Apk)[(long long)i*KP+42+d]));
  if(a>=b) m = 0.f;
  segmax[s*128+d]=m;
}

// ---------- per-step fused: pool = relu(segmax @ W_pool + b_pool); contrib = pool @ Wx[128:256,:] ----------
__global__ void s1bc_poolcontrib(const float* __restrict__ segmax,
                                 const void* __restrict__ Wpool, const void* __restrict__ bpool,
                                 const void* __restrict__ Wx, const int* __restrict__ flags,
                                 float* __restrict__ contrib){
  __shared__ float pl[128];
  int s = blockIdx.x;
  int t = threadIdx.x;
  bool bf = flags[0]!=0;
  const float* sm = segmax + s*128;
  // phase 1: 256 threads, 2 per dim (halves of the K=128 dot)
  {
    int cc = t&127, half = t>>7;
    float acc = 0.f;
    for(int k=half*64;k<half*64+64;k++) acc += sm[k]*ldf(Wpool,k*128+cc,bf);
    // combine halves via LDS
    __shared__ float part[256];
    part[t]=acc;
    __syncthreads();
    if(t<128) pl[t] = fmaxf(part[t]+part[t+128]+ldf(bpool,t,bf), 0.f);
    __syncthreads();
  }
  // phase 2: 256 threads, 2 outputs each
  float* cb = contrib + (long long)s*512;
  #pragma unroll
  for(int r=0;r<2;r++){
    int cc = t + r*256;
    float acc=0.f;
    for(int k=0;k<128;k++) acc += pl[k]*ldf(Wx,(128+k)*512+cc,bf);
    cb[cc]=acc;
  }
}

// ---------- per-step: MFMA gates GEMM (M=64, N=512, K=192) + fused LSTM pointwise ----------
// 8 waves; wave w owns dims [w*16, w*16+16) of ALL FOUR gates -> LSTM pointwise is thread-local.
// acc = 4 m-tiles x 4 gates x 4 = 64 regs; no LDS, no barriers.
__launch_bounds__(512,4)
__global__ void s2_mfma(short* __restrict__ Apk, float* __restrict__ c_st,
                        const short* __restrict__ wT, const float* __restrict__ bias,
                        const float* __restrict__ contrib,
                        const void* __restrict__ segids, const int* __restrict__ flags,
                        const unsigned char* __restrict__ mask){
  const int tid = threadIdx.x;
  const int w   = tid>>6;
  const int l   = tid&63;
  const int lm  = l&15;
  const int lq  = l>>4;
  const int P0  = blockIdx.x*64;
  const bool i64 = flags[1]!=0;

  float4v acc[4][4];
  #pragma unroll
  for(int mt=0;mt<4;mt++)
    #pragma unroll
    for(int g=0;g<4;g++) acc[mt][g] = (float4v)(0.f);

  const short* ap = Apk + (long long)(P0+lm)*KP + lq*8;
  const short* bp[4];
  #pragma unroll
  for(int g=0;g<4;g++)
    bp[g] = wT + (long long)(g*128 + w*16 + lm)*KP + lq*8;

  #pragma unroll
  for(int kc=0;kc<6;kc++){
    short8 a0 = *(const short8*)(ap + 0*16*KP + kc*32);
    short8 a1 = *(const short8*)(ap + 1*16*KP + kc*32);
    short8 a2 = *(const short8*)(ap + 2*16*KP + kc*32);
    short8 a3 = *(const short8*)(ap + 3*16*KP + kc*32);
    short8 b0 = *(const short8*)(bp[0] + kc*32);
    short8 b1 = *(const short8*)(bp[1] + kc*32);
    short8 b2 = *(const short8*)(bp[2] + kc*32);
    short8 b3 = *(const short8*)(bp[3] + kc*32);
    acc[0][0] = __builtin_amdgcn_mfma_f32_16x16x32_bf16(a0, b0, acc[0][0],0,0,0);
    acc[0][1] = __builtin_amdgcn_mfma_f32_16x16x32_bf16(a0, b1, acc[0][1],0,0,0);
    acc[0][2] = __builtin_amdgcn_mfma_f32_16x16x32_bf16(a0, b2, acc[0][2],0,0,0);
    acc[0][3] = __builtin_amdgcn_mfma_f32_16x16x32_bf16(a0, b3, acc[0][3],0,0,0);
    acc[1][0] = __builtin_amdgcn_mfma_f32_16x16x32_bf16(a1, b0, acc[1][0],0,0,0);
    acc[1][1] = __builtin_amdgcn_mfma_f32_16x16x32_bf16(a1, b1, acc[1][1],0,0,0);
    acc[1][2] = __builtin_amdgcn_mfma_f32_16x16x32_bf16(a1, b2, acc[1][2],0,0,0);
    acc[1][3] = __builtin_amdgcn_mfma_f32_16x16x32_bf16(a1, b3, acc[1][3],0,0,0);
    acc[2][0] = __builtin_amdgcn_mfma_f32_16x16x32_bf16(a2, b0, acc[2][0],0,0,0);
    acc[2][1] = __builtin_amdgcn_mfma_f32_16x16x32_bf16(a2, b1, acc[2][1],0,0,0);
    acc[2][2] = __builtin_amdgcn_mfma_f32_16x16x32_bf16(a2, b2, acc[2][2],0,0,0);
    acc[2][3] = __builtin_amdgcn_mfma_f32_16x16x32_bf16(a2, b3, acc[2][3],0,0,0);
    acc[3][0] = __builtin_amdgcn_mfma_f32_16x16x32_bf16(a3, b0, acc[3][0],0,0,0);
    acc[3][1] = __builtin_amdgcn_mfma_f32_16x16x32_bf16(a3, b1, acc[3][1],0,0,0);
    acc[3][2] = __builtin_amdgcn_mfma_f32_16x16x32_bf16(a3, b2, acc[3][2],0,0,0);
    acc[3][3] = __builtin_amdgcn_mfma_f32_16x16x32_bf16(a3, b3, acc[3][3],0,0,0);
  }

  const int d = w*16 + lm;
  float bi0 = bias[      d];
  float bi1 = bias[128 + d];
  float bi2 = bias[256 + d];
  float bi3 = bias[384 + d];

  #pragma unroll
  for(int mt=0;mt<4;mt++){
    #pragma unroll
    for(int q=0;q<4;q++){
      int p = P0 + mt*16 + lq*4 + q;
      if(!mask[p]) continue;              // h2/c2 = old values: skip write entirely
      int sg = ldseg(segids,p,i64);
      const float* cb = contrib + (long long)sg*512;
      float gi = acc[mt][0][q] + bi0 + cb[      d];
      float gf = acc[mt][1][q] + bi1 + cb[128 + d];
      float gg = acc[mt][2][q] + bi2 + cb[256 + d];
      float go = acc[mt][3][q] + bi3 + cb[384 + d];
      float* crow = c_st + (long long)p*128;
      bf16* hrow = (bf16*)Apk + (long long)p*KP + 42;
      float co = crow[d];
      float cn = sigm(gf)*co + sigm(gi)*tanh_f(gg);
      float hn = sigm(go)*tanh_f(cn);
      crow[d] = cn;
      hrow[d] = __float2bfloat16(hn);
    }
  }
}

// ---------- per-step epilogue: out head, rel/pos, alpha softmax, fields->dtp, traj ----------
__global__ void s3_post(const short* __restrict__ Apk_c, short* __restrict__ Apk,
                        float* __restrict__ rel, float* __restrict__ pos, float* __restrict__ al,
                        const void* __restrict__ Wout, const void* __restrict__ bout,
                        const void* __restrict__ fieldA, const void* __restrict__ trans,
                        const int* __restrict__ flags,
                        const unsigned char* __restrict__ mask, void* __restrict__ traj, int t){
  int grp = threadIdx.x>>6, lane = threadIdx.x&63;
  int p = blockIdx.x*4+grp;
  bool bf = flags[0]!=0;
  const bf16* hrow = (const bf16*)Apk_c + (long long)p*KP + 42;
  float h0 = b2f(hrow[lane]), h1 = b2f(hrow[64+lane]);
  float o0 = h0*ldf(Wout,lane*2,bf)   + h1*ldf(Wout,(64+lane)*2,bf);
  float o1 = h0*ldf(Wout,lane*2+1,bf) + h1*ldf(Wout,(64+lane)*2+1,bf);
  for(int m=1;m<64;m<<=1){ o0 += __shfl_xor(o0,m); o1 += __shfl_xor(o1,m); }
  o0 += ldf(bout,0,bf); o1 += ldf(bout,1,bf);
  bool msk = mask[p]!=0;
  float r0 = rel[p*2], r1 = rel[p*2+1];
  if(msk){ r0=o0; r1=o1; }
  float pn0 = pos[p*2]+r0, pn1 = pos[p*2+1]+r1;
  // alpha matvec via shuffle broadcast: lane j<20 computes sum_i al[i]*trans[i][j]
  float a_l = (lane<NKK)? al[(long long)p*NKK+lane] : 0.f;
  float ad = -INFINITY;
  if(lane<NKK){
    float a2=0.f;
    #pragma unroll
    for(int i=0;i<NKK;i++) a2 += __shfl(a_l,i)*ldf(trans,i*NKK+lane,bf);
    ad = a2;
  }
  float mx = ad;
  for(int m=1;m<64;m<<=1) mx = fmaxf(mx, __shfl_xor(mx,m));
  float e = (lane<NKK)? __expf(ad-mx) : 0.f;
  float se = e;
  for(int m=1;m<64;m<<=1) se += __shfl_xor(se,m);
  float alp = e/se;
  if(msk && lane<NKK) al[(long long)p*NKK+lane] = alp;
  float alq = __shfl(alp, lane>>1);
  if(msk && lane<2*NKK){
    int kk=lane>>1, ee=lane&1;
    float fp = pn0*ldf(fieldA,kk*4+ee,bf) + pn1*ldf(fieldA,kk*4+2+ee,bf);
    ((bf16*)Apk)[(long long)p*KP+2+lane] = __float2bfloat16(fp*alq);
  }
  if(lane==0){
    if(msk){
      ((bf16*)Apk)[(long long)p*KP+0] = __float2bfloat16(r0);
      ((bf16*)Apk)[(long long)p*KP+1] = __float2bfloat16(r1);
    }
    rel[p*2]=r0; rel[p*2+1]=r1;
    pos[p*2]=pn0; pos[p*2+1]=pn1;
    long long base = (long long)t*N_PTS*2 + (long long)p*2;
    stf(traj, base,   r0, bf);
    stf(traj, base+1, r1, bf);
  }
}

extern "C" void kernel_launch(void* const* d_in, const int* in_sizes, int n_in,
                              void* d_out, int out_size, void* d_ws, size_t ws_size,
                              hipStream_t stream){
  const void* sf      = d_in[0];
  const void* lastpos = d_in[1];
  const void* alpha0  = d_in[2];
  const void* fd0     = d_in[3];
  const void* Wpos    = d_in[4];
  const void* bpos    = d_in[5];
  const void* Wfld    = d_in[6];
  const void* bfld    = d_in[7];
  const void* Wpool   = d_in[8];
  const void* bpool   = d_in[9];
  const void* Wx      = d_in[10];
  const void* Wh      = d_in[11];
  const void* blstm   = d_in[12];
  const void* Wout    = d_in[13];
  const void* bout    = d_in[14];
  const void* fieldA  = d_in[15];
  const void* trans   = d_in[16];
  const void* segids  = d_in[17];
  const unsigned char* maskraw = (const unsigned char*)d_in[18];

  char* ws = (char*)d_ws;
  size_t o = 0;
  auto alc = [&](size_t b){ size_t r=o; o=(o+b+255)&~(size_t)255; return r; };
  short* Apk     = (short*)(ws+alc((size_t)N_PTS*KP*2));
  float* c_st    = (float*)(ws+alc((size_t)N_PTS*128*4));
  float* rel     = (float*)(ws+alc((size_t)N_PTS*2*4));
  float* pos     = (float*)(ws+alc((size_t)N_PTS*2*4));
  float* al      = (float*)(ws+alc((size_t)N_PTS*20*4));
  int*   segst   = (int*)  (ws+alc((size_t)(NSEG+1)*4));
  float* segmax  = (float*)(ws+alc((size_t)NSEG*128*4));
  float* contrib = (float*)(ws+alc((size_t)NSEG*512*4));
  short* wT      = (short*)(ws+alc((size_t)512*KP*2));
  float* bias    = (float*)(ws+alc((size_t)512*4));
  unsigned char* mask = (unsigned char*)(ws+alc((size_t)N_PTS));
  int*   flags   = (int*)  (ws+alc(64));

  k_probe<<<1,64,0,stream>>>((const unsigned short*)Wx, (const int*)segids, maskraw, flags);
  k_conv<<<512,256,0,stream>>>(maskraw, flags, mask);
  k_segstart<<<33,256,0,stream>>>(segids, flags, segst);
  k_fold<<<386,256,0,stream>>>(Wpos,bpos,Wfld,bfld,Wx,Wh,blstm,flags,wT,bias);
  k_init<<<32768,256,0,stream>>>(sf,lastpos,alpha0,fd0,Wout,bout,flags,Apk,c_st,rel,pos,al,d_out);

  for(int t=1;t<PRED;t++){
    s1a_segmax<<<NSEG,128,0,stream>>>(Apk, segst, segmax);
    s1bc_poolcontrib<<<NSEG,256,0,stream>>>(segmax, Wpool, bpool, Wx, flags, contrib);
    s2_mfma<<<N_PTS/64,512,0,stream>>>(Apk, c_st, wT, bias, contrib, segids, flags, mask);
    s3_post<<<N_PTS/4,256,0,stream>>>(Apk, Apk, rel, pos, al, Wout, bout, fieldA, trans, flags, mask, d_out, t);
  }
}

// Round 5
// 3106.158 us; speedup vs baseline: 1.4623x; 1.4623x over previous
//
#include <hip/hip_runtime.h>
#include <hip/hip_bf16.h>
#include <math.h>

#define N_PTS 131072
#define NSEG  8192
#define NKK   20
#define PRED  12
#define KP    192   // padded K: 2 rel + 40 dtp + 128 h + 22 zero

typedef __hip_bfloat16 bf16;
typedef __attribute__((ext_vector_type(8))) short short8;
typedef __attribute__((ext_vector_type(4))) float float4v;

__device__ __forceinline__ float b2f(bf16 x){ return __bfloat162float(x); }
__device__ __forceinline__ float sigm(float x){ return 1.0f/(1.0f+__expf(-x)); }
__device__ __forceinline__ float tanh_f(float x){
  x = fminf(15.f, fmaxf(-15.f, x));
  float e = __expf(2.f*x);
  return (e-1.f)/(e+1.f);
}
__device__ __forceinline__ float ldf(const void* p, long long i, bool bf){
  return bf ? __bfloat162float(((const bf16*)p)[i]) : ((const float*)p)[i];
}
__device__ __forceinline__ int ldseg(const void* p, long long i, bool i64){
  return i64 ? (int)(((const long long*)p)[i]) : ((const int*)p)[i];
}
__device__ __forceinline__ void stf(void* p, long long i, float v, bool bf){
  if(bf) ((bf16*)p)[i] = __float2bfloat16(v);
  else   ((float*)p)[i] = v;
}

// ---------- dtype probes: flags[0]=float-is-bf16, flags[1]=segids-int64, flags[2]=mask mode(0=i32,1=byte,2=i64)
__global__ void k_probe(const unsigned short* __restrict__ wx,
                        const int* __restrict__ seg,
                        const unsigned char* __restrict__ msk,
                        int* __restrict__ flags){
  int lane = threadIdx.x & 63;
  unsigned short h1 = wx[2*lane], h2 = wx[128+2*lane];
  int e1 = (h1>>7)&255, e2 = (h2>>7)&255;
  bool p1 = (e1>=100 && e1<=132), p2 = (e2>=100 && e2<=132);
  int cnt = __popcll(__ballot(p1)) + __popcll(__ballot(p2));
  int v = seg[65536+lane];
  int zc = __popcll(__ballot((lane&1) && v==0));
  bool nz1=false, nz2=false;
  for(int i=lane;i<4096;i+=64){
    unsigned char b = msk[i];
    if((i&3)!=0 && b) nz1=true;
    if((i&7)==4 && b) nz2=true;
  }
  unsigned long long b1 = __ballot(nz1), b2 = __ballot(nz2);
  if(lane==0){
    flags[0] = (cnt>=64) ? 1 : 0;
    flags[1] = (zc>=24) ? 1 : 0;
    flags[2] = b1 ? 1 : (b2 ? 0 : 2);
  }
}

__global__ void k_conv(const unsigned char* __restrict__ mraw, const int* __restrict__ flags,
                       unsigned char* __restrict__ mask){
  int i = blockIdx.x*256+threadIdx.x;
  if(i>=N_PTS) return;
  int mode = flags[2];
  unsigned char v;
  if(mode==1)      v = mraw[i]!=0;
  else if(mode==0) v = ((const int*)mraw)[i]!=0;
  else             v = ((const long long*)mraw)[i]!=0;
  mask[i]=v;
}

__global__ void k_segstart(const void* __restrict__ seg, const int* __restrict__ flags,
                           int* __restrict__ start){
  int s = blockIdx.x*256+threadIdx.x;
  if(s>NSEG) return;
  bool i64 = flags[1]!=0;
  int lo=0, hi=N_PTS;
  while(lo<hi){ int mid=(lo+hi)>>1; if(ldseg(seg,mid,i64)<s) lo=mid+1; else hi=mid; }
  start[s]=lo;
}

// ---------- fold weights: wT[512][192] bf16 B-layout, bias fp32[512],
//            wpoolT[128][128] bf16 (n-major), wxT2[512][128] bf16 (n-major, rows 128:256 of Wx)
__global__ void k_fold(const void* __restrict__ Wpos, const void* __restrict__ bpos,
                       const void* __restrict__ Wfld, const void* __restrict__ bfld,
                       const void* __restrict__ Wx,   const void* __restrict__ Wh,
                       const void* __restrict__ blstm, const int* __restrict__ flags,
                       short* __restrict__ wT, float* __restrict__ bias,
                       short* __restrict__ wpoolT, const void* __restrict__ Wpool,
                       short* __restrict__ wxT2){
  int idx = blockIdx.x*256+threadIdx.x;
  bool bf = flags[0]!=0;
  if(idx < 512*KP){
    int n = idx/KP, k = idx - n*KP;
    float v;
    if(k<2){
      float a=0; for(int j=0;j<64;j++) a += ldf(Wpos,k*64+j,bf)*ldf(Wx,j*512+n,bf);
      v=a;
    } else if(k<42){
      int kk=k-2; float a=0; for(int j=0;j<64;j++) a += ldf(Wfld,kk*64+j,bf)*ldf(Wx,(64+j)*512+n,bf);
      v=a;
    } else if(k<170){
      v = ldf(Wh,(long long)(k-42)*512+n,bf);
    } else v = 0.f;
    ((bf16*)wT)[(long long)n*KP+k] = __float2bfloat16(v);
  } else if(idx < 512*KP+512){
    int c = idx - 512*KP;
    float a=ldf(blstm,c,bf);
    for(int j=0;j<64;j++) a += ldf(bpos,j,bf)*ldf(Wx,j*512+c,bf) + ldf(bfld,j,bf)*ldf(Wx,(64+j)*512+c,bf);
    bias[c]=a;
  } else if(idx < 512*KP+512+128*128){
    int j = idx - (512*KP+512);
    int n = j>>7, k = j&127;
    ((bf16*)wpoolT)[j] = __float2bfloat16(ldf(Wpool,k*128+n,bf));
  } else if(idx < 512*KP+512+128*128+512*128){
    int j = idx - (512*KP+512+128*128);
    int n = j>>7, k = j&127;
    ((bf16*)wxT2)[j] = __float2bfloat16(ldf(Wx,(long long)(128+k)*512+n,bf));
  }
}

// ---------- init: build Apk[p][192], c=0, rel/pos fp32, al fp32, traj[0] ----------
__global__ void k_init(const void* __restrict__ sf, const void* __restrict__ lastpos,
                       const void* __restrict__ alpha0, const void* __restrict__ fd0,
                       const void* __restrict__ Wout, const void* __restrict__ bout,
                       const int* __restrict__ flags,
                       short* __restrict__ Apk, float* __restrict__ c,
                       float* __restrict__ rel, float* __restrict__ pos,
                       float* __restrict__ al, void* __restrict__ traj){
  int grp = threadIdx.x>>6, lane = threadIdx.x&63;
  int p = blockIdx.x*4+grp;
  bool bf = flags[0]!=0;
  bf16* Ap = (bf16*)Apk + (long long)p*KP;
  float h0 = ldf(sf,(long long)p*128+lane,bf);
  float h1 = ldf(sf,(long long)p*128+64+lane,bf);
  Ap[42+lane]      = __float2bfloat16(h0);
  Ap[42+64+lane]   = __float2bfloat16(h1);
  c[(long long)p*128+lane]=0.f; c[(long long)p*128+64+lane]=0.f;
  float o0 = h0*ldf(Wout,lane*2,bf)   + h1*ldf(Wout,(64+lane)*2,bf);
  float o1 = h0*ldf(Wout,lane*2+1,bf) + h1*ldf(Wout,(64+lane)*2+1,bf);
  for(int m=1;m<64;m<<=1){ o0 += __shfl_xor(o0,m); o1 += __shfl_xor(o1,m); }
  o0 += ldf(bout,0,bf); o1 += ldf(bout,1,bf);
  float a = 0.f;
  if(lane<NKK) a = ldf(alpha0,(long long)p*NKK+lane,bf);
  float s = a;
  for(int m=1;m<64;m<<=1) s += __shfl_xor(s,m);
  float aln = a/s;
  if(lane<NKK) al[(long long)p*NKK+lane] = aln;
  float alq = __shfl(aln, lane>>1);
  if(lane<2*NKK) Ap[2+lane] = __float2bfloat16(ldf(fd0,(long long)p*2*NKK+lane,bf)*alq);
  if(lane<22)    Ap[170+lane] = __float2bfloat16(0.f);
  if(lane==0){
    Ap[0]=__float2bfloat16(o0); Ap[1]=__float2bfloat16(o1);
    rel[p*2]=o0; rel[p*2+1]=o1;
    pos[p*2]   = ldf(lastpos,p*2,bf)  +o0;
    pos[p*2+1] = ldf(lastpos,p*2+1,bf)+o1;
    stf(traj, (long long)p*2,   o0, bf);
    stf(traj, (long long)p*2+1, o1, bf);
  }
}

// ---------- per-step: segment max over h -> bf16 segmax (A-layout row-major [seg][128]) ----------
__global__ void s1a_segmax(const short* __restrict__ Apk, const int* __restrict__ start,
                           short* __restrict__ segmax_bf){
  int s = blockIdx.x;
  int d = threadIdx.x;
  int a = start[s], b = start[s+1];
  float m = -INFINITY;
  for(int i=a;i<b;i++) m = fmaxf(m, b2f(((const bf16*)Apk)[(long long)i*KP+42+d]));
  if(a>=b) m = 0.f;
  ((bf16*)segmax_bf)[s*128+d] = __float2bfloat16(m);
}

// ---------- per-step: pool = relu(segmax @ Wpool + bpool) via MFMA -> bf16 [seg][128] ----------
// M=8192 (64/block), N=128 (8 waves x 16), K=128. No LDS, no barriers.
__launch_bounds__(512,4)
__global__ void s1p_pool(const short* __restrict__ segmax_bf, const short* __restrict__ wpoolT,
                         const void* __restrict__ bpool, const int* __restrict__ flags,
                         short* __restrict__ pool_bf){
  const int tid = threadIdx.x;
  const int w = tid>>6, l = tid&63, lm = l&15, lq = l>>4;
  const int S0 = blockIdx.x*64;
  float4v acc[4];
  #pragma unroll
  for(int mt=0;mt<4;mt++) acc[mt] = (float4v)(0.f);
  const short* ap = segmax_bf + (long long)(S0+lm)*128 + lq*8;
  const short* bp = wpoolT + (long long)(w*16+lm)*128 + lq*8;
  #pragma unroll
  for(int kc=0;kc<4;kc++){
    short8 b = *(const short8*)(bp + kc*32);
    #pragma unroll
    for(int mt=0;mt<4;mt++){
      short8 a = *(const short8*)(ap + mt*16*128 + kc*32);
      acc[mt] = __builtin_amdgcn_mfma_f32_16x16x32_bf16(a, b, acc[mt],0,0,0);
    }
  }
  bool bf = flags[0]!=0;
  const int n = w*16+lm;
  float bv = ldf(bpool,n,bf);
  #pragma unroll
  for(int mt=0;mt<4;mt++)
    #pragma unroll
    for(int q=0;q<4;q++){
      int s = S0 + mt*16 + lq*4 + q;
      ((bf16*)pool_bf)[(long long)s*128+n] = __float2bfloat16(fmaxf(acc[mt][q]+bv, 0.f));
    }
}

// ---------- per-step: contrib = pool @ Wx[128:256,:] via MFMA -> fp32 [seg][512] ----------
// M=8192 (64/block), N=512 (8 waves x 64), K=128.
__launch_bounds__(512,4)
__global__ void s1c_mfma(const short* __restrict__ pool_bf, const short* __restrict__ wxT2,
                         float* __restrict__ contrib){
  const int tid = threadIdx.x;
  const int w = tid>>6, l = tid&63, lm = l&15, lq = l>>4;
  const int S0 = blockIdx.x*64;
  float4v acc[4][4];
  #pragma unroll
  for(int mt=0;mt<4;mt++)
    #pragma unroll
    for(int j=0;j<4;j++) acc[mt][j] = (float4v)(0.f);
  const short* ap = pool_bf + (long long)(S0+lm)*128 + lq*8;
  const short* bp[4];
  #pragma unroll
  for(int j=0;j<4;j++) bp[j] = wxT2 + (long long)(w*64+j*16+lm)*128 + lq*8;
  #pragma unroll
  for(int kc=0;kc<4;kc++){
    short8 a[4], b[4];
    #pragma unroll
    for(int mt=0;mt<4;mt++) a[mt] = *(const short8*)(ap + mt*16*128 + kc*32);
    #pragma unroll
    for(int j=0;j<4;j++) b[j] = *(const short8*)(bp[j] + kc*32);
    #pragma unroll
    for(int mt=0;mt<4;mt++)
      #pragma unroll
      for(int j=0;j<4;j++)
        acc[mt][j] = __builtin_amdgcn_mfma_f32_16x16x32_bf16(a[mt], b[j], acc[mt][j],0,0,0);
  }
  #pragma unroll
  for(int mt=0;mt<4;mt++)
    #pragma unroll
    for(int j=0;j<4;j++)
      #pragma unroll
      for(int q=0;q<4;q++){
        int s = S0 + mt*16 + lq*4 + q;
        contrib[(long long)s*512 + w*64 + j*16 + lm] = acc[mt][j][q];
      }
}

// ---------- per-step: MFMA gates GEMM (M=64, N=512, K=192) + fused LSTM pointwise ----------
__launch_bounds__(512,4)
__global__ void s2_mfma(short* __restrict__ Apk, float* __restrict__ c_st,
                        const short* __restrict__ wT, const float* __restrict__ bias,
                        const float* __restrict__ contrib,
                        const void* __restrict__ segids, const int* __restrict__ flags,
                        const unsigned char* __restrict__ mask){
  const int tid = threadIdx.x;
  const int w   = tid>>6;
  const int l   = tid&63;
  const int lm  = l&15;
  const int lq  = l>>4;
  const int P0  = blockIdx.x*64;
  const bool i64 = flags[1]!=0;

  float4v acc[4][4];
  #pragma unroll
  for(int mt=0;mt<4;mt++)
    #pragma unroll
    for(int g=0;g<4;g++) acc[mt][g] = (float4v)(0.f);

  const short* ap = Apk + (long long)(P0+lm)*KP + lq*8;
  const short* bp[4];
  #pragma unroll
  for(int g=0;g<4;g++)
    bp[g] = wT + (long long)(g*128 + w*16 + lm)*KP + lq*8;

  #pragma unroll
  for(int kc=0;kc<6;kc++){
    short8 a0 = *(const short8*)(ap + 0*16*KP + kc*32);
    short8 a1 = *(const short8*)(ap + 1*16*KP + kc*32);
    short8 a2 = *(const short8*)(ap + 2*16*KP + kc*32);
    short8 a3 = *(const short8*)(ap + 3*16*KP + kc*32);
    short8 b0 = *(const short8*)(bp[0] + kc*32);
    short8 b1 = *(const short8*)(bp[1] + kc*32);
    short8 b2 = *(const short8*)(bp[2] + kc*32);
    short8 b3 = *(const short8*)(bp[3] + kc*32);
    acc[0][0] = __builtin_amdgcn_mfma_f32_16x16x32_bf16(a0, b0, acc[0][0],0,0,0);
    acc[0][1] = __builtin_amdgcn_mfma_f32_16x16x32_bf16(a0, b1, acc[0][1],0,0,0);
    acc[0][2] = __builtin_amdgcn_mfma_f32_16x16x32_bf16(a0, b2, acc[0][2],0,0,0);
    acc[0][3] = __builtin_amdgcn_mfma_f32_16x16x32_bf16(a0, b3, acc[0][3],0,0,0);
    acc[1][0] = __builtin_amdgcn_mfma_f32_16x16x32_bf16(a1, b0, acc[1][0],0,0,0);
    acc[1][1] = __builtin_amdgcn_mfma_f32_16x16x32_bf16(a1, b1, acc[1][1],0,0,0);
    acc[1][2] = __builtin_amdgcn_mfma_f32_16x16x32_bf16(a1, b2, acc[1][2],0,0,0);
    acc[1][3] = __builtin_amdgcn_mfma_f32_16x16x32_bf16(a1, b3, acc[1][3],0,0,0);
    acc[2][0] = __builtin_amdgcn_mfma_f32_16x16x32_bf16(a2, b0, acc[2][0],0,0,0);
    acc[2][1] = __builtin_amdgcn_mfma_f32_16x16x32_bf16(a2, b1, acc[2][1],0,0,0);
    acc[2][2] = __builtin_amdgcn_mfma_f32_16x16x32_bf16(a2, b2, acc[2][2],0,0,0);
    acc[2][3] = __builtin_amdgcn_mfma_f32_16x16x32_bf16(a2, b3, acc[2][3],0,0,0);
    acc[3][0] = __builtin_amdgcn_mfma_f32_16x16x32_bf16(a3, b0, acc[3][0],0,0,0);
    acc[3][1] = __builtin_amdgcn_mfma_f32_16x16x32_bf16(a3, b1, acc[3][1],0,0,0);
    acc[3][2] = __builtin_amdgcn_mfma_f32_16x16x32_bf16(a3, b2, acc[3][2],0,0,0);
    acc[3][3] = __builtin_amdgcn_mfma_f32_16x16x32_bf16(a3, b3, acc[3][3],0,0,0);
  }

  const int d = w*16 + lm;
  float bi0 = bias[      d];
  float bi1 = bias[128 + d];
  float bi2 = bias[256 + d];
  float bi3 = bias[384 + d];

  #pragma unroll
  for(int mt=0;mt<4;mt++){
    #pragma unroll
    for(int q=0;q<4;q++){
      int p = P0 + mt*16 + lq*4 + q;
      if(!mask[p]) continue;
      int sg = ldseg(segids,p,i64);
      const float* cb = contrib + (long long)sg*512;
      float gi = acc[mt][0][q] + bi0 + cb[      d];
      float gf = acc[mt][1][q] + bi1 + cb[128 + d];
      float gg = acc[mt][2][q] + bi2 + cb[256 + d];
      float go = acc[mt][3][q] + bi3 + cb[384 + d];
      float* crow = c_st + (long long)p*128;
      bf16* hrow = (bf16*)Apk + (long long)p*KP + 42;
      float co = crow[d];
      float cn = sigm(gf)*co + sigm(gi)*tanh_f(gg);
      float hn = sigm(go)*tanh_f(cn);
      crow[d] = cn;
      hrow[d] = __float2bfloat16(hn);
    }
  }
}

// ---------- per-step epilogue: out head, rel/pos, alpha softmax, fields->dtp, traj ----------
__global__ void s3_post(const short* __restrict__ Apk_c, short* __restrict__ Apk,
                        float* __restrict__ rel, float* __restrict__ pos, float* __restrict__ al,
                        const void* __restrict__ Wout, const void* __restrict__ bout,
                        const void* __restrict__ fieldA, const void* __restrict__ trans,
                        const int* __restrict__ flags,
                        const unsigned char* __restrict__ mask, void* __restrict__ traj, int t){
  int grp = threadIdx.x>>6, lane = threadIdx.x&63;
  int p = blockIdx.x*4+grp;
  bool bf = flags[0]!=0;
  const bf16* hrow = (const bf16*)Apk_c + (long long)p*KP + 42;
  float h0 = b2f(hrow[lane]), h1 = b2f(hrow[64+lane]);
  float o0 = h0*ldf(Wout,lane*2,bf)   + h1*ldf(Wout,(64+lane)*2,bf);
  float o1 = h0*ldf(Wout,lane*2+1,bf) + h1*ldf(Wout,(64+lane)*2+1,bf);
  for(int m=1;m<64;m<<=1){ o0 += __shfl_xor(o0,m); o1 += __shfl_xor(o1,m); }
  o0 += ldf(bout,0,bf); o1 += ldf(bout,1,bf);
  bool msk = mask[p]!=0;
  float r0 = rel[p*2], r1 = rel[p*2+1];
  if(msk){ r0=o0; r1=o1; }
  float pn0 = pos[p*2]+r0, pn1 = pos[p*2+1]+r1;
  float a_l = (lane<NKK)? al[(long long)p*NKK+lane] : 0.f;
  float ad = -INFINITY;
  if(lane<NKK){
    float a2=0.f;
    #pragma unroll
    for(int i=0;i<NKK;i++) a2 += __shfl(a_l,i)*ldf(trans,i*NKK+lane,bf);
    ad = a2;
  }
  float mx = ad;
  for(int m=1;m<64;m<<=1) mx = fmaxf(mx, __shfl_xor(mx,m));
  float e = (lane<NKK)? __expf(ad-mx) : 0.f;
  float se = e;
  for(int m=1;m<64;m<<=1) se += __shfl_xor(se,m);
  float alp = e/se;
  if(msk && lane<NKK) al[(long long)p*NKK+lane] = alp;
  float alq = __shfl(alp, lane>>1);
  if(msk && lane<2*NKK){
    int kk=lane>>1, ee=lane&1;
    float fp = pn0*ldf(fieldA,kk*4+ee,bf) + pn1*ldf(fieldA,kk*4+2+ee,bf);
    ((bf16*)Apk)[(long long)p*KP+2+lane] = __float2bfloat16(fp*alq);
  }
  if(lane==0){
    if(msk){
      ((bf16*)Apk)[(long long)p*KP+0] = __float2bfloat16(r0);
      ((bf16*)Apk)[(long long)p*KP+1] = __float2bfloat16(r1);
    }
    rel[p*2]=r0; rel[p*2+1]=r1;
    pos[p*2]=pn0; pos[p*2+1]=pn1;
    long long base = (long long)t*N_PTS*2 + (long long)p*2;
    stf(traj, base,   r0, bf);
    stf(traj, base+1, r1, bf);
  }
}

extern "C" void kernel_launch(void* const* d_in, const int* in_sizes, int n_in,
                              void* d_out, int out_size, void* d_ws, size_t ws_size,
                              hipStream_t stream){
  const void* sf      = d_in[0];
  const void* lastpos = d_in[1];
  const void* alpha0  = d_in[2];
  const void* fd0     = d_in[3];
  const void* Wpos    = d_in[4];
  const void* bpos    = d_in[5];
  const void* Wfld    = d_in[6];
  const void* bfld    = d_in[7];
  const void* Wpool   = d_in[8];
  const void* bpool   = d_in[9];
  const void* Wx      = d_in[10];
  const void* Wh      = d_in[11];
  const void* blstm   = d_in[12];
  const void* Wout    = d_in[13];
  const void* bout    = d_in[14];
  const void* fieldA  = d_in[15];
  const void* trans   = d_in[16];
  const void* segids  = d_in[17];
  const unsigned char* maskraw = (const unsigned char*)d_in[18];

  char* ws = (char*)d_ws;
  size_t o = 0;
  auto alc = [&](size_t b){ size_t r=o; o=(o+b+255)&~(size_t)255; return r; };
  short* Apk       = (short*)(ws+alc((size_t)N_PTS*KP*2));
  float* c_st      = (float*)(ws+alc((size_t)N_PTS*128*4));
  float* rel       = (float*)(ws+alc((size_t)N_PTS*2*4));
  float* pos       = (float*)(ws+alc((size_t)N_PTS*2*4));
  float* al        = (float*)(ws+alc((size_t)N_PTS*20*4));
  int*   segst     = (int*)  (ws+alc((size_t)(NSEG+1)*4));
  short* segmax_bf = (short*)(ws+alc((size_t)NSEG*128*2));
  short* pool_bf   = (short*)(ws+alc((size_t)NSEG*128*2));
  float* contrib   = (float*)(ws+alc((size_t)NSEG*512*4));
  short* wT        = (short*)(ws+alc((size_t)512*KP*2));
  float* bias      = (float*)(ws+alc((size_t)512*4));
  short* wpoolT    = (short*)(ws+alc((size_t)128*128*2));
  short* wxT2      = (short*)(ws+alc((size_t)512*128*2));
  unsigned char* mask = (unsigned char*)(ws+alc((size_t)N_PTS));
  int*   flags     = (int*)  (ws+alc(64));

  k_probe<<<1,64,0,stream>>>((const unsigned short*)Wx, (const int*)segids, maskraw, flags);
  k_conv<<<512,256,0,stream>>>(maskraw, flags, mask);
  k_segstart<<<33,256,0,stream>>>(segids, flags, segst);
  k_fold<<<706,256,0,stream>>>(Wpos,bpos,Wfld,bfld,Wx,Wh,blstm,flags,wT,bias,wpoolT,Wpool,wxT2);
  k_init<<<32768,256,0,stream>>>(sf,lastpos,alpha0,fd0,Wout,bout,flags,Apk,c_st,rel,pos,al,d_out);

  for(int t=1;t<PRED;t++){
    s1a_segmax<<<NSEG,128,0,stream>>>(Apk, segst, segmax_bf);
    s1p_pool<<<NSEG/64,512,0,stream>>>(segmax_bf, wpoolT, bpool, flags, pool_bf);
    s1c_mfma<<<NSEG/64,512,0,stream>>>(pool_bf, wxT2, contrib);
    s2_mfma<<<N_PTS/64,512,0,stream>>>(Apk, c_st, wT, bias, contrib, segids, flags, mask);
    s3_post<<<N_PTS/4,256,0,stream>>>(Apk, Apk, rel, pos, al, Wout, bout, fieldA, trans, flags, mask, d_out, t);
  }
}

// Round 6
// 3018.816 us; speedup vs baseline: 1.5046x; 1.0289x over previous
//
#include <hip/hip_runtime.h>
#include <hip/hip_bf16.h>
#include <math.h>

#define N_PTS 131072
#define NSEG  8192
#define NKK   20
#define PRED  12
#define KP    192   // padded K: 2 rel + 40 dtp + 128 h + 22 zero

typedef __hip_bfloat16 bf16;
typedef __attribute__((ext_vector_type(8))) short short8;
typedef __attribute__((ext_vector_type(4))) float float4v;

__device__ __forceinline__ float b2f(bf16 x){ return __bfloat162float(x); }
__device__ __forceinline__ float sigm(float x){ return 1.0f/(1.0f+__expf(-x)); }
__device__ __forceinline__ float tanh_f(float x){
  x = fminf(15.f, fmaxf(-15.f, x));
  float e = __expf(2.f*x);
  return (e-1.f)/(e+1.f);
}
__device__ __forceinline__ float ldf(const void* p, long long i, bool bf){
  return bf ? __bfloat162float(((const bf16*)p)[i]) : ((const float*)p)[i];
}
__device__ __forceinline__ int ldseg(const void* p, long long i, bool i64){
  return i64 ? (int)(((const long long*)p)[i]) : ((const int*)p)[i];
}
__device__ __forceinline__ void stf(void* p, long long i, float v, bool bf){
  if(bf) ((bf16*)p)[i] = __float2bfloat16(v);
  else   ((float*)p)[i] = v;
}

// ---------- dtype probes: flags[0]=float-is-bf16, flags[1]=segids-int64, flags[2]=mask mode(0=i32,1=byte,2=i64)
__global__ void k_probe(const unsigned short* __restrict__ wx,
                        const int* __restrict__ seg,
                        const unsigned char* __restrict__ msk,
                        int* __restrict__ flags){
  int lane = threadIdx.x & 63;
  unsigned short h1 = wx[2*lane], h2 = wx[128+2*lane];
  int e1 = (h1>>7)&255, e2 = (h2>>7)&255;
  bool p1 = (e1>=100 && e1<=132), p2 = (e2>=100 && e2<=132);
  int cnt = __popcll(__ballot(p1)) + __popcll(__ballot(p2));
  int v = seg[65536+lane];
  int zc = __popcll(__ballot((lane&1) && v==0));
  bool nz1=false, nz2=false;
  for(int i=lane;i<4096;i+=64){
    unsigned char b = msk[i];
    if((i&3)!=0 && b) nz1=true;
    if((i&7)==4 && b) nz2=true;
  }
  unsigned long long b1 = __ballot(nz1), b2 = __ballot(nz2);
  if(lane==0){
    flags[0] = (cnt>=64) ? 1 : 0;
    flags[1] = (zc>=24) ? 1 : 0;
    flags[2] = b1 ? 1 : (b2 ? 0 : 2);
  }
}

__global__ void k_conv(const unsigned char* __restrict__ mraw, const int* __restrict__ flags,
                       unsigned char* __restrict__ mask){
  int i = blockIdx.x*256+threadIdx.x;
  if(i>=N_PTS) return;
  int mode = flags[2];
  unsigned char v;
  if(mode==1)      v = mraw[i]!=0;
  else if(mode==0) v = ((const int*)mraw)[i]!=0;
  else             v = ((const long long*)mraw)[i]!=0;
  mask[i]=v;
}

__global__ void k_segstart(const void* __restrict__ seg, const int* __restrict__ flags,
                           int* __restrict__ start){
  int s = blockIdx.x*256+threadIdx.x;
  if(s>NSEG) return;
  bool i64 = flags[1]!=0;
  int lo=0, hi=N_PTS;
  while(lo<hi){ int mid=(lo+hi)>>1; if(ldseg(seg,mid,i64)<s) lo=mid+1; else hi=mid; }
  start[s]=lo;
}

// ---------- fold weights: wT[512][192] bf16 B-layout, bias fp32[512],
//            wpoolT[128][128] bf16 (n-major), wxT2[512][128] bf16 (n-major, rows 128:256 of Wx)
__global__ void k_fold(const void* __restrict__ Wpos, const void* __restrict__ bpos,
                       const void* __restrict__ Wfld, const void* __restrict__ bfld,
                       const void* __restrict__ Wx,   const void* __restrict__ Wh,
                       const void* __restrict__ blstm, const int* __restrict__ flags,
                       short* __restrict__ wT, float* __restrict__ bias,
                       short* __restrict__ wpoolT, const void* __restrict__ Wpool,
                       short* __restrict__ wxT2){
  int idx = blockIdx.x*256+threadIdx.x;
  bool bf = flags[0]!=0;
  if(idx < 512*KP){
    int n = idx/KP, k = idx - n*KP;
    float v;
    if(k<2){
      float a=0; for(int j=0;j<64;j++) a += ldf(Wpos,k*64+j,bf)*ldf(Wx,j*512+n,bf);
      v=a;
    } else if(k<42){
      int kk=k-2; float a=0; for(int j=0;j<64;j++) a += ldf(Wfld,kk*64+j,bf)*ldf(Wx,(64+j)*512+n,bf);
      v=a;
    } else if(k<170){
      v = ldf(Wh,(long long)(k-42)*512+n,bf);
    } else v = 0.f;
    ((bf16*)wT)[(long long)n*KP+k] = __float2bfloat16(v);
  } else if(idx < 512*KP+512){
    int c = idx - 512*KP;
    float a=ldf(blstm,c,bf);
    for(int j=0;j<64;j++) a += ldf(bpos,j,bf)*ldf(Wx,j*512+c,bf) + ldf(bfld,j,bf)*ldf(Wx,(64+j)*512+c,bf);
    bias[c]=a;
  } else if(idx < 512*KP+512+128*128){
    int j = idx - (512*KP+512);
    int n = j>>7, k = j&127;
    ((bf16*)wpoolT)[j] = __float2bfloat16(ldf(Wpool,k*128+n,bf));
  } else if(idx < 512*KP+512+128*128+512*128){
    int j = idx - (512*KP+512+128*128);
    int n = j>>7, k = j&127;
    ((bf16*)wxT2)[j] = __float2bfloat16(ldf(Wx,(long long)(128+k)*512+n,bf));
  }
}

// ---------- init: build Apk[p][192], c=0, rel/pos fp32, al fp32, traj[0] ----------
__global__ void k_init(const void* __restrict__ sf, const void* __restrict__ lastpos,
                       const void* __restrict__ alpha0, const void* __restrict__ fd0,
                       const void* __restrict__ Wout, const void* __restrict__ bout,
                       const int* __restrict__ flags,
                       short* __restrict__ Apk, float* __restrict__ c,
                       float* __restrict__ rel, float* __restrict__ pos,
                       float* __restrict__ al, void* __restrict__ traj){
  int grp = threadIdx.x>>6, lane = threadIdx.x&63;
  int p = blockIdx.x*4+grp;
  bool bf = flags[0]!=0;
  bf16* Ap = (bf16*)Apk + (long long)p*KP;
  float h0 = ldf(sf,(long long)p*128+lane,bf);
  float h1 = ldf(sf,(long long)p*128+64+lane,bf);
  Ap[42+lane]      = __float2bfloat16(h0);
  Ap[42+64+lane]   = __float2bfloat16(h1);
  c[(long long)p*128+lane]=0.f; c[(long long)p*128+64+lane]=0.f;
  float o0 = h0*ldf(Wout,lane*2,bf)   + h1*ldf(Wout,(64+lane)*2,bf);
  float o1 = h0*ldf(Wout,lane*2+1,bf) + h1*ldf(Wout,(64+lane)*2+1,bf);
  for(int m=1;m<64;m<<=1){ o0 += __shfl_xor(o0,m); o1 += __shfl_xor(o1,m); }
  o0 += ldf(bout,0,bf); o1 += ldf(bout,1,bf);
  float a = 0.f;
  if(lane<NKK) a = ldf(alpha0,(long long)p*NKK+lane,bf);
  float s = a;
  for(int m=1;m<64;m<<=1) s += __shfl_xor(s,m);
  float aln = a/s;
  if(lane<NKK) al[(long long)p*NKK+lane] = aln;
  float alq = __shfl(aln, lane>>1);
  if(lane<2*NKK) Ap[2+lane] = __float2bfloat16(ldf(fd0,(long long)p*2*NKK+lane,bf)*alq);
  if(lane<22)    Ap[170+lane] = __float2bfloat16(0.f);
  if(lane==0){
    Ap[0]=__float2bfloat16(o0); Ap[1]=__float2bfloat16(o1);
    rel[p*2]=o0; rel[p*2+1]=o1;
    pos[p*2]   = ldf(lastpos,p*2,bf)  +o0;
    pos[p*2+1] = ldf(lastpos,p*2+1,bf)+o1;
    stf(traj, (long long)p*2,   o0, bf);
    stf(traj, (long long)p*2+1, o1, bf);
  }
}

// ---------- per-step: segment max over h -> bf16 segmax (A-layout row-major [seg][128]) ----------
__global__ void s1a_segmax(const short* __restrict__ Apk, const int* __restrict__ start,
                           short* __restrict__ segmax_bf){
  int s = blockIdx.x;
  int d = threadIdx.x;
  int a = start[s], b = start[s+1];
  float m = -INFINITY;
  for(int i=a;i<b;i++) m = fmaxf(m, b2f(((const bf16*)Apk)[(long long)i*KP+42+d]));
  if(a>=b) m = 0.f;
  ((bf16*)segmax_bf)[s*128+d] = __float2bfloat16(m);
}

// ---------- per-step: pool = relu(segmax @ Wpool + bpool) via MFMA -> bf16 [seg][128] ----------
// M=8192 (32/block -> 256 blocks), N=128 (8 waves x 16), K=128.
__launch_bounds__(512,2)
__global__ void s1p_pool(const short* __restrict__ segmax_bf, const short* __restrict__ wpoolT,
                         const void* __restrict__ bpool, const int* __restrict__ flags,
                         short* __restrict__ pool_bf){
  const int tid = threadIdx.x;
  const int w = tid>>6, l = tid&63, lm = l&15, lq = l>>4;
  const int S0 = blockIdx.x*32;
  float4v acc[2];
  acc[0]=(float4v)(0.f); acc[1]=(float4v)(0.f);
  const short* ap = segmax_bf + (long long)(S0+lm)*128 + lq*8;
  const short* bp = wpoolT + (long long)(w*16+lm)*128 + lq*8;
  #pragma unroll
  for(int kc=0;kc<4;kc++){
    short8 b = *(const short8*)(bp + kc*32);
    short8 a0 = *(const short8*)(ap + 0*16*128 + kc*32);
    short8 a1 = *(const short8*)(ap + 1*16*128 + kc*32);
    acc[0] = __builtin_amdgcn_mfma_f32_16x16x32_bf16(a0, b, acc[0],0,0,0);
    acc[1] = __builtin_amdgcn_mfma_f32_16x16x32_bf16(a1, b, acc[1],0,0,0);
  }
  bool bf = flags[0]!=0;
  const int n = w*16+lm;
  float bv = ldf(bpool,n,bf);
  #pragma unroll
  for(int mt=0;mt<2;mt++)
    #pragma unroll
    for(int q=0;q<4;q++){
      int s = S0 + mt*16 + lq*4 + q;
      ((bf16*)pool_bf)[(long long)s*128+n] = __float2bfloat16(fmaxf(acc[mt][q]+bv, 0.f));
    }
}

// ---------- per-step: contrib = pool @ Wx[128:256,:] via MFMA -> fp32 [seg][512] ----------
// M=8192 (32/block -> 256 blocks), N=512 (8 waves x 64), K=128.
__launch_bounds__(512,2)
__global__ void s1c_mfma(const short* __restrict__ pool_bf, const short* __restrict__ wxT2,
                         float* __restrict__ contrib){
  const int tid = threadIdx.x;
  const int w = tid>>6, l = tid&63, lm = l&15, lq = l>>4;
  const int S0 = blockIdx.x*32;
  float4v acc[2][4];
  #pragma unroll
  for(int mt=0;mt<2;mt++)
    #pragma unroll
    for(int j=0;j<4;j++) acc[mt][j] = (float4v)(0.f);
  const short* ap = pool_bf + (long long)(S0+lm)*128 + lq*8;
  const short* bp[4];
  #pragma unroll
  for(int j=0;j<4;j++) bp[j] = wxT2 + (long long)(w*64+j*16+lm)*128 + lq*8;
  #pragma unroll
  for(int kc=0;kc<4;kc++){
    short8 a[2], b[4];
    #pragma unroll
    for(int mt=0;mt<2;mt++) a[mt] = *(const short8*)(ap + mt*16*128 + kc*32);
    #pragma unroll
    for(int j=0;j<4;j++) b[j] = *(const short8*)(bp[j] + kc*32);
    #pragma unroll
    for(int mt=0;mt<2;mt++)
      #pragma unroll
      for(int j=0;j<4;j++)
        acc[mt][j] = __builtin_amdgcn_mfma_f32_16x16x32_bf16(a[mt], b[j], acc[mt][j],0,0,0);
  }
  #pragma unroll
  for(int mt=0;mt<2;mt++)
    #pragma unroll
    for(int j=0;j<4;j++)
      #pragma unroll
      for(int q=0;q<4;q++){
        int s = S0 + mt*16 + lq*4 + q;
        contrib[(long long)s*512 + w*64 + j*16 + lm] = acc[mt][j][q];
      }
}

// ---------- per-step: MFMA gates GEMM (M=64, N=512, K=192) + fused LSTM pointwise ----------
// Explicit 2-deep register prefetch pipeline; epilogue metadata (mask/segids) hoisted
// above the K-loop so its latency hides under the MFMAs. launch_bounds(512,2): 256-reg
// budget so the compiler keeps cur+nxt staging (64 regs) + 64 acc in flight without sinking.
__launch_bounds__(512,2)
__global__ void s2_mfma(short* __restrict__ Apk, float* __restrict__ c_st,
                        const short* __restrict__ wT, const float* __restrict__ bias,
                        const float* __restrict__ contrib,
                        const void* __restrict__ segids, const int* __restrict__ flags,
                        const unsigned char* __restrict__ mask){
  const int tid = threadIdx.x;
  const int w   = tid>>6;
  const int l   = tid&63;
  const int lm  = l&15;
  const int lq  = l>>4;
  const int P0  = blockIdx.x*64;
  const bool i64 = flags[1]!=0;

  // hoisted epilogue metadata: mask bytes + segment ids for the 16 points this thread owns
  uchar4 mk[4];
  int sg[4][4];
  #pragma unroll
  for(int mt=0;mt<4;mt++){
    int pb = P0 + mt*16 + lq*4;
    mk[mt] = *(const uchar4*)(mask + pb);
    #pragma unroll
    for(int q=0;q<4;q++) sg[mt][q] = ldseg(segids, pb+q, i64);
  }

  float4v acc[4][4];
  #pragma unroll
  for(int mt=0;mt<4;mt++)
    #pragma unroll
    for(int g=0;g<4;g++) acc[mt][g] = (float4v)(0.f);

  const short* ap = Apk + (long long)(P0+lm)*KP + lq*8;
  const short* bp = wT + (long long)(w*16+lm)*KP + lq*8;   // gate g at +g*128*KP

  short8 a_c[4], b_c[4], a_n[4], b_n[4];
  #pragma unroll
  for(int m=0;m<4;m++){
    a_c[m] = *(const short8*)(ap + m*16*KP);
    b_c[m] = *(const short8*)(bp + m*128*KP);
  }
  #pragma unroll
  for(int kc=0;kc<6;kc++){
    if(kc<5){
      #pragma unroll
      for(int m=0;m<4;m++){
        a_n[m] = *(const short8*)(ap + m*16*KP  + (kc+1)*32);
        b_n[m] = *(const short8*)(bp + m*128*KP + (kc+1)*32);
      }
    }
    #pragma unroll
    for(int mt=0;mt<4;mt++)
      #pragma unroll
      for(int g=0;g<4;g++)
        acc[mt][g] = __builtin_amdgcn_mfma_f32_16x16x32_bf16(a_c[mt], b_c[g], acc[mt][g],0,0,0);
    #pragma unroll
    for(int m=0;m<4;m++){ a_c[m]=a_n[m]; b_c[m]=b_n[m]; }
  }

  const int d = w*16 + lm;
  float bi0 = bias[      d];
  float bi1 = bias[128 + d];
  float bi2 = bias[256 + d];
  float bi3 = bias[384 + d];

  #pragma unroll
  for(int mt=0;mt<4;mt++){
    #pragma unroll
    for(int q=0;q<4;q++){
      unsigned char mq = (q==0)?mk[mt].x:(q==1)?mk[mt].y:(q==2)?mk[mt].z:mk[mt].w;
      if(!mq) continue;
      int p = P0 + mt*16 + lq*4 + q;
      const float* cb = contrib + (long long)sg[mt][q]*512;
      float gi = acc[mt][0][q] + bi0 + cb[      d];
      float gf = acc[mt][1][q] + bi1 + cb[128 + d];
      float gg = acc[mt][2][q] + bi2 + cb[256 + d];
      float go = acc[mt][3][q] + bi3 + cb[384 + d];
      float* crow = c_st + (long long)p*128;
      bf16* hrow = (bf16*)Apk + (long long)p*KP + 42;
      float co = crow[d];
      float cn = sigm(gf)*co + sigm(gi)*tanh_f(gg);
      float hn = sigm(go)*tanh_f(cn);
      crow[d] = cn;
      hrow[d] = __float2bfloat16(hn);
    }
  }
}

// ---------- per-step epilogue: out head, rel/pos, alpha softmax, fields->dtp, traj ----------
__global__ void s3_post(const short* __restrict__ Apk_c, short* __restrict__ Apk,
                        float* __restrict__ rel, float* __restrict__ pos, float* __restrict__ al,
                        const void* __restrict__ Wout, const void* __restrict__ bout,
                        const void* __restrict__ fieldA, const void* __restrict__ trans,
                        const int* __restrict__ flags,
                        const unsigned char* __restrict__ mask, void* __restrict__ traj, int t){
  int grp = threadIdx.x>>6, lane = threadIdx.x&63;
  int p = blockIdx.x*4+grp;
  bool bf = flags[0]!=0;
  const bf16* hrow = (const bf16*)Apk_c + (long long)p*KP + 42;
  float h0 = b2f(hrow[lane]), h1 = b2f(hrow[64+lane]);
  float o0 = h0*ldf(Wout,lane*2,bf)   + h1*ldf(Wout,(64+lane)*2,bf);
  float o1 = h0*ldf(Wout,lane*2+1,bf) + h1*ldf(Wout,(64+lane)*2+1,bf);
  for(int m=1;m<64;m<<=1){ o0 += __shfl_xor(o0,m); o1 += __shfl_xor(o1,m); }
  o0 += ldf(bout,0,bf); o1 += ldf(bout,1,bf);
  bool msk = mask[p]!=0;
  float r0 = rel[p*2], r1 = rel[p*2+1];
  if(msk){ r0=o0; r1=o1; }
  float pn0 = pos[p*2]+r0, pn1 = pos[p*2+1]+r1;
  float a_l = (lane<NKK)? al[(long long)p*NKK+lane] : 0.f;
  float ad = -INFINITY;
  if(lane<NKK){
    float a2=0.f;
    #pragma unroll
    for(int i=0;i<NKK;i++) a2 += __shfl(a_l,i)*ldf(trans,i*NKK+lane,bf);
    ad = a2;
  }
  float mx = ad;
  for(int m=1;m<64;m<<=1) mx = fmaxf(mx, __shfl_xor(mx,m));
  float e = (lane<NKK)? __expf(ad-mx) : 0.f;
  float se = e;
  for(int m=1;m<64;m<<=1) se += __shfl_xor(se,m);
  float alp = e/se;
  if(msk && lane<NKK) al[(long long)p*NKK+lane] = alp;
  float alq = __shfl(alp, lane>>1);
  if(msk && lane<2*NKK){
    int kk=lane>>1, ee=lane&1;
    float fp = pn0*ldf(fieldA,kk*4+ee,bf) + pn1*ldf(fieldA,kk*4+2+ee,bf);
    ((bf16*)Apk)[(long long)p*KP+2+lane] = __float2bfloat16(fp*alq);
  }
  if(lane==0){
    if(msk){
      ((bf16*)Apk)[(long long)p*KP+0] = __float2bfloat16(r0);
      ((bf16*)Apk)[(long long)p*KP+1] = __float2bfloat16(r1);
    }
    rel[p*2]=r0; rel[p*2+1]=r1;
    pos[p*2]=pn0; pos[p*2+1]=pn1;
    long long base = (long long)t*N_PTS*2 + (long long)p*2;
    stf(traj, base,   r0, bf);
    stf(traj, base+1, r1, bf);
  }
}

extern "C" void kernel_launch(void* const* d_in, const int* in_sizes, int n_in,
                              void* d_out, int out_size, void* d_ws, size_t ws_size,
                              hipStream_t stream){
  const void* sf      = d_in[0];
  const void* lastpos = d_in[1];
  const void* alpha0  = d_in[2];
  const void* fd0     = d_in[3];
  const void* Wpos    = d_in[4];
  const void* bpos    = d_in[5];
  const void* Wfld    = d_in[6];
  const void* bfld    = d_in[7];
  const void* Wpool   = d_in[8];
  const void* bpool   = d_in[9];
  const void* Wx      = d_in[10];
  const void* Wh      = d_in[11];
  const void* blstm   = d_in[12];
  const void* Wout    = d_in[13];
  const void* bout    = d_in[14];
  const void* fieldA  = d_in[15];
  const void* trans   = d_in[16];
  const void* segids  = d_in[17];
  const unsigned char* maskraw = (const unsigned char*)d_in[18];

  char* ws = (char*)d_ws;
  size_t o = 0;
  auto alc = [&](size_t b){ size_t r=o; o=(o+b+255)&~(size_t)255; return r; };
  short* Apk       = (short*)(ws+alc((size_t)N_PTS*KP*2));
  float* c_st      = (float*)(ws+alc((size_t)N_PTS*128*4));
  float* rel       = (float*)(ws+alc((size_t)N_PTS*2*4));
  float* pos       = (float*)(ws+alc((size_t)N_PTS*2*4));
  float* al        = (float*)(ws+alc((size_t)N_PTS*20*4));
  int*   segst     = (int*)  (ws+alc((size_t)(NSEG+1)*4));
  short* segmax_bf = (short*)(ws+alc((size_t)NSEG*128*2));
  short* pool_bf   = (short*)(ws+alc((size_t)NSEG*128*2));
  float* contrib   = (float*)(ws+alc((size_t)NSEG*512*4));
  short* wT        = (short*)(ws+alc((size_t)512*KP*2));
  float* bias      = (float*)(ws+alc((size_t)512*4));
  short* wpoolT    = (short*)(ws+alc((size_t)128*128*2));
  short* wxT2      = (short*)(ws+alc((size_t)512*128*2));
  unsigned char* mask = (unsigned char*)(ws+alc((size_t)N_PTS));
  int*   flags     = (int*)  (ws+alc(64));

  k_probe<<<1,64,0,stream>>>((const unsigned short*)Wx, (const int*)segids, maskraw, flags);
  k_conv<<<512,256,0,stream>>>(maskraw, flags, mask);
  k_segstart<<<33,256,0,stream>>>(segids, flags, segst);
  k_fold<<<706,256,0,stream>>>(Wpos,bpos,Wfld,bfld,Wx,Wh,blstm,flags,wT,bias,wpoolT,Wpool,wxT2);
  k_init<<<32768,256,0,stream>>>(sf,lastpos,alpha0,fd0,Wout,bout,flags,Apk,c_st,rel,pos,al,d_out);

  for(int t=1;t<PRED;t++){
    s1a_segmax<<<NSEG,128,0,stream>>>(Apk, segst, segmax_bf);
    s1p_pool<<<NSEG/32,512,0,stream>>>(segmax_bf, wpoolT, bpool, flags, pool_bf);
    s1c_mfma<<<NSEG/32,512,0,stream>>>(pool_bf, wxT2, contrib);
    s2_mfma<<<N_PTS/64,512,0,stream>>>(Apk, c_st, wT, bias, contrib, segids, flags, mask);
    s3_post<<<N_PTS/4,256,0,stream>>>(Apk, Apk, rel, pos, al, Wout, bout, fieldA, trans, flags, mask, d_out, t);
  }
}

// Round 8
// 2417.890 us; speedup vs baseline: 1.8786x; 1.2485x over previous
//
#include <hip/hip_runtime.h>
#include <hip/hip_bf16.h>
#include <math.h>

#define N_PTS 131072
#define NSEG  8192
#define NKK   20
#define PRED  12
#define KP    192   // padded K: 2 rel + 40 dtp + 128 h + 22 zero

typedef __hip_bfloat16 bf16;
typedef __attribute__((ext_vector_type(8))) short short8;
typedef __attribute__((ext_vector_type(4))) float float4v;

__device__ __forceinline__ float b2f(bf16 x){ return __bfloat162float(x); }
__device__ __forceinline__ float sigm(float x){ return 1.0f/(1.0f+__expf(-x)); }
__device__ __forceinline__ float tanh_f(float x){
  x = fminf(15.f, fmaxf(-15.f, x));
  float e = __expf(2.f*x);
  return (e-1.f)/(e+1.f);
}
__device__ __forceinline__ float ldf(const void* p, long long i, bool bf){
  return bf ? __bfloat162float(((const bf16*)p)[i]) : ((const float*)p)[i];
}
__device__ __forceinline__ int ldseg(const void* p, long long i, bool i64){
  return i64 ? (int)(((const long long*)p)[i]) : ((const int*)p)[i];
}
__device__ __forceinline__ void stf(void* p, long long i, float v, bool bf){
  if(bf) ((bf16*)p)[i] = __float2bfloat16(v);
  else   ((float*)p)[i] = v;
}

// ---------- dtype probes: flags[0]=float-is-bf16, flags[1]=segids-int64, flags[2]=mask mode(0=i32,1=byte,2=i64)
__global__ void k_probe(const unsigned short* __restrict__ wx,
                        const int* __restrict__ seg,
                        const unsigned char* __restrict__ msk,
                        int* __restrict__ flags){
  int lane = threadIdx.x & 63;
  unsigned short h1 = wx[2*lane], h2 = wx[128+2*lane];
  int e1 = (h1>>7)&255, e2 = (h2>>7)&255;
  bool p1 = (e1>=100 && e1<=132), p2 = (e2>=100 && e2<=132);
  int cnt = __popcll(__ballot(p1)) + __popcll(__ballot(p2));
  int v = seg[65536+lane];
  int zc = __popcll(__ballot((lane&1) && v==0));
  bool nz1=false, nz2=false;
  for(int i=lane;i<4096;i+=64){
    unsigned char b = msk[i];
    if((i&3)!=0 && b) nz1=true;
    if((i&7)==4 && b) nz2=true;
  }
  unsigned long long b1 = __ballot(nz1), b2 = __ballot(nz2);
  if(lane==0){
    flags[0] = (cnt>=64) ? 1 : 0;
    flags[1] = (zc>=24) ? 1 : 0;
    flags[2] = b1 ? 1 : (b2 ? 0 : 2);
  }
}

__global__ void k_conv(const unsigned char* __restrict__ mraw, const int* __restrict__ flags,
                       unsigned char* __restrict__ mask){
  int i = blockIdx.x*256+threadIdx.x;
  if(i>=N_PTS) return;
  int mode = flags[2];
  unsigned char v;
  if(mode==1)      v = mraw[i]!=0;
  else if(mode==0) v = ((const int*)mraw)[i]!=0;
  else             v = ((const long long*)mraw)[i]!=0;
  mask[i]=v;
}

__global__ void k_segstart(const void* __restrict__ seg, const int* __restrict__ flags,
                           int* __restrict__ start){
  int s = blockIdx.x*256+threadIdx.x;
  if(s>NSEG) return;
  bool i64 = flags[1]!=0;
  int lo=0, hi=N_PTS;
  while(lo<hi){ int mid=(lo+hi)>>1; if(ldseg(seg,mid,i64)<s) lo=mid+1; else hi=mid; }
  start[s]=lo;
}

// ---------- fold weights.
// wTs: swizzled B operand for s2. Element (n,k), n=g*128+n':
//   ntg=n'/16, lm=n'%16, kc=k/32, lq=(k%32)/8, j=k%8
//   addr = ((g*8+ntg)*6 + kc)*512 + lq*128 + lm*8 + j   -> each (tile,chunk) is one contiguous 1KB
// wpoolT[128][128] bf16 (n-major), wxT2[512][128] bf16 (n-major), bias fp32[512]
__global__ void k_fold(const void* __restrict__ Wpos, const void* __restrict__ bpos,
                       const void* __restrict__ Wfld, const void* __restrict__ bfld,
                       const void* __restrict__ Wx,   const void* __restrict__ Wh,
                       const void* __restrict__ blstm, const int* __restrict__ flags,
                       short* __restrict__ wTs, float* __restrict__ bias,
                       short* __restrict__ wpoolT, const void* __restrict__ Wpool,
                       short* __restrict__ wxT2){
  int idx = blockIdx.x*256+threadIdx.x;
  bool bf = flags[0]!=0;
  if(idx < 512*KP){
    int n = idx/KP, k = idx - n*KP;
    float v;
    if(k<2){
      float a=0; for(int j=0;j<64;j++) a += ldf(Wpos,k*64+j,bf)*ldf(Wx,j*512+n,bf);
      v=a;
    } else if(k<42){
      int kk=k-2; float a=0; for(int j=0;j<64;j++) a += ldf(Wfld,kk*64+j,bf)*ldf(Wx,(64+j)*512+n,bf);
      v=a;
    } else if(k<170){
      v = ldf(Wh,(long long)(k-42)*512+n,bf);
    } else v = 0.f;
    int g = n>>7, np = n&127;
    int ntg = np>>4, lm = np&15;
    int kc = k>>5, lq = (k&31)>>3, j = k&7;
    long long addr = ((long long)((g*8+ntg)*6 + kc))*512 + lq*128 + lm*8 + j;
    ((bf16*)wTs)[addr] = __float2bfloat16(v);
  } else if(idx < 512*KP+512){
    int c = idx - 512*KP;
    float a=ldf(blstm,c,bf);
    for(int j=0;j<64;j++) a += ldf(bpos,j,bf)*ldf(Wx,j*512+c,bf) + ldf(bfld,j,bf)*ldf(Wx,(64+j)*512+c,bf);
    bias[c]=a;
  } else if(idx < 512*KP+512+128*128){
    int j = idx - (512*KP+512);
    int n = j>>7, k = j&127;
    ((bf16*)wpoolT)[j] = __float2bfloat16(ldf(Wpool,k*128+n,bf));
  } else if(idx < 512*KP+512+128*128+512*128){
    int j = idx - (512*KP+512+128*128);
    int n = j>>7, k = j&127;
    ((bf16*)wxT2)[j] = __float2bfloat16(ldf(Wx,(long long)(128+k)*512+n,bf));
  }
}

// ---------- init: build Apk[p][192], c=0, rel/pos fp32, al fp32, traj[0] ----------
__global__ void k_init(const void* __restrict__ sf, const void* __restrict__ lastpos,
                       const void* __restrict__ alpha0, const void* __restrict__ fd0,
                       const void* __restrict__ Wout, const void* __restrict__ bout,
                       const int* __restrict__ flags,
                       short* __restrict__ Apk, float* __restrict__ c,
                       float* __restrict__ rel, float* __restrict__ pos,
                       float* __restrict__ al, void* __restrict__ traj){
  int grp = threadIdx.x>>6, lane = threadIdx.x&63;
  int p = blockIdx.x*4+grp;
  bool bf = flags[0]!=0;
  bf16* Ap = (bf16*)Apk + (long long)p*KP;
  float h0 = ldf(sf,(long long)p*128+lane,bf);
  float h1 = ldf(sf,(long long)p*128+64+lane,bf);
  Ap[42+lane]      = __float2bfloat16(h0);
  Ap[42+64+lane]   = __float2bfloat16(h1);
  c[(long long)p*128+lane]=0.f; c[(long long)p*128+64+lane]=0.f;
  float o0 = h0*ldf(Wout,lane*2,bf)   + h1*ldf(Wout,(64+lane)*2,bf);
  float o1 = h0*ldf(Wout,lane*2+1,bf) + h1*ldf(Wout,(64+lane)*2+1,bf);
  for(int m=1;m<64;m<<=1){ o0 += __shfl_xor(o0,m); o1 += __shfl_xor(o1,m); }
  o0 += ldf(bout,0,bf); o1 += ldf(bout,1,bf);
  float a = 0.f;
  if(lane<NKK) a = ldf(alpha0,(long long)p*NKK+lane,bf);
  float s = a;
  for(int m=1;m<64;m<<=1) s += __shfl_xor(s,m);
  float aln = a/s;
  if(lane<NKK) al[(long long)p*NKK+lane] = aln;
  float alq = __shfl(aln, lane>>1);
  if(lane<2*NKK) Ap[2+lane] = __float2bfloat16(ldf(fd0,(long long)p*2*NKK+lane,bf)*alq);
  if(lane<22)    Ap[170+lane] = __float2bfloat16(0.f);
  if(lane==0){
    Ap[0]=__float2bfloat16(o0); Ap[1]=__float2bfloat16(o1);
    rel[p*2]=o0; rel[p*2+1]=o1;
    pos[p*2]   = ldf(lastpos,p*2,bf)  +o0;
    pos[p*2+1] = ldf(lastpos,p*2+1,bf)+o1;
    stf(traj, (long long)p*2,   o0, bf);
    stf(traj, (long long)p*2+1, o1, bf);
  }
}

// ---------- per-step: segment max over h -> bf16 segmax (A-layout row-major [seg][128]) ----------
__global__ void s1a_segmax(const short* __restrict__ Apk, const int* __restrict__ start,
                           short* __restrict__ segmax_bf){
  int s = blockIdx.x;
  int d = threadIdx.x;
  int a = start[s], b = start[s+1];
  float m = -INFINITY;
  for(int i=a;i<b;i++) m = fmaxf(m, b2f(((const bf16*)Apk)[(long long)i*KP+42+d]));
  if(a>=b) m = 0.f;
  ((bf16*)segmax_bf)[s*128+d] = __float2bfloat16(m);
}

// ---------- per-step: pool = relu(segmax @ Wpool + bpool) via MFMA -> bf16 [seg][128] ----------
__launch_bounds__(512,2)
__global__ void s1p_pool(const short* __restrict__ segmax_bf, const short* __restrict__ wpoolT,
                         const void* __restrict__ bpool, const int* __restrict__ flags,
                         short* __restrict__ pool_bf){
  const int tid = threadIdx.x;
  const int w = tid>>6, l = tid&63, lm = l&15, lq = l>>4;
  const int S0 = blockIdx.x*32;
  float4v acc[2];
  acc[0]=(float4v)(0.f); acc[1]=(float4v)(0.f);
  const short* ap = segmax_bf + (long long)(S0+lm)*128 + lq*8;
  const short* bp = wpoolT + (long long)(w*16+lm)*128 + lq*8;
  #pragma unroll
  for(int kc=0;kc<4;kc++){
    short8 b = *(const short8*)(bp + kc*32);
    short8 a0 = *(const short8*)(ap + 0*16*128 + kc*32);
    short8 a1 = *(const short8*)(ap + 1*16*128 + kc*32);
    acc[0] = __builtin_amdgcn_mfma_f32_16x16x32_bf16(a0, b, acc[0],0,0,0);
    acc[1] = __builtin_amdgcn_mfma_f32_16x16x32_bf16(a1, b, acc[1],0,0,0);
  }
  bool bf = flags[0]!=0;
  const int n = w*16+lm;
  float bv = ldf(bpool,n,bf);
  #pragma unroll
  for(int mt=0;mt<2;mt++)
    #pragma unroll
    for(int q=0;q<4;q++){
      int s = S0 + mt*16 + lq*4 + q;
      ((bf16*)pool_bf)[(long long)s*128+n] = __float2bfloat16(fmaxf(acc[mt][q]+bv, 0.f));
    }
}

// ---------- per-step: contrib = pool @ Wx[128:256,:] via MFMA -> fp32 [seg][512] ----------
__launch_bounds__(512,2)
__global__ void s1c_mfma(const short* __restrict__ pool_bf, const short* __restrict__ wxT2,
                         float* __restrict__ contrib){
  const int tid = threadIdx.x;
  const int w = tid>>6, l = tid&63, lm = l&15, lq = l>>4;
  const int S0 = blockIdx.x*32;
  float4v acc[2][4];
  #pragma unroll
  for(int mt=0;mt<2;mt++)
    #pragma unroll
    for(int j=0;j<4;j++) acc[mt][j] = (float4v)(0.f);
  const short* ap = pool_bf + (long long)(S0+lm)*128 + lq*8;
  const short* bp[4];
  #pragma unroll
  for(int j=0;j<4;j++) bp[j] = wxT2 + (long long)(w*64+j*16+lm)*128 + lq*8;
  #pragma unroll
  for(int kc=0;kc<4;kc++){
    short8 a[2], b[4];
    #pragma unroll
    for(int mt=0;mt<2;mt++) a[mt] = *(const short8*)(ap + mt*16*128 + kc*32);
    #pragma unroll
    for(int j=0;j<4;j++) b[j] = *(const short8*)(bp[j] + kc*32);
    #pragma unroll
    for(int mt=0;mt<2;mt++)
      #pragma unroll
      for(int j=0;j<4;j++)
        acc[mt][j] = __builtin_amdgcn_mfma_f32_16x16x32_bf16(a[mt], b[j], acc[mt][j],0,0,0);
  }
  #pragma unroll
  for(int mt=0;mt<2;mt++)
    #pragma unroll
    for(int j=0;j<4;j++)
      #pragma unroll
      for(int q=0;q<4;q++){
        int s = S0 + mt*16 + lq*4 + q;
        contrib[(long long)s*512 + w*64 + j*16 + lm] = acc[mt][j][q];
      }
}

// ---------- per-step: MFMA gates GEMM (M=32/block, N=512, K=192) + fused LSTM pointwise ----------
// 256-thread (4-wave) blocks, 4096 blocks. Block owns ALL 512 N-dims for its 32 points
// (no inter-block A/h race); wave w owns dims [w*32,w*32+32) of each gate (thread-local LSTM).
// __syncthreads() between K-loop and epilogue closes the intra-block read/write race on Apk h.
// B loads fully coalesced via wTs swizzle (1KB contiguous per fragment).
__launch_bounds__(256,3)
__global__ void s2_mfma(short* __restrict__ Apk, float* __restrict__ c_st,
                        const short* __restrict__ wTs, const float* __restrict__ bias,
                        const float* __restrict__ contrib,
                        const void* __restrict__ segids, const int* __restrict__ flags,
                        const unsigned char* __restrict__ mask){
  const int tid = threadIdx.x;
  const int w   = tid>>6;
  const int l   = tid&63;
  const int lm  = l&15;
  const int lq  = l>>4;
  const int P0  = blockIdx.x*32;
  const bool i64 = flags[1]!=0;

  // hoisted epilogue metadata: 8 points per thread
  uchar4 mk[2];
  int sg[2][4];
  #pragma unroll
  for(int mt=0;mt<2;mt++){
    int pb = P0 + mt*16 + lq*4;
    mk[mt] = *(const uchar4*)(mask + pb);
    #pragma unroll
    for(int q=0;q<4;q++) sg[mt][q] = ldseg(segids, pb+q, i64);
  }

  float4v acc[2][4][2];   // [m-tile][gate][j] -> 64 VGPRs
  #pragma unroll
  for(int mt=0;mt<2;mt++)
    #pragma unroll
    for(int g=0;g<4;g++)
      #pragma unroll
      for(int j=0;j<2;j++) acc[mt][g][j] = (float4v)(0.f);

  const short* ap = Apk + (long long)(P0+lm)*KP + lq*8;
  const short* bp = wTs + lq*128 + lm*8;   // fragment (g,j,kc) at + ((g*8 + w*2 + j)*6 + kc)*512

  #pragma unroll
  for(int kc=0;kc<6;kc++){
    short8 a0 = *(const short8*)(ap + 0*16*KP + kc*32);
    short8 a1 = *(const short8*)(ap + 1*16*KP + kc*32);
    short8 b[4][2];
    #pragma unroll
    for(int g=0;g<4;g++)
      #pragma unroll
      for(int j=0;j<2;j++)
        b[g][j] = *(const short8*)(bp + ((long long)((g*8 + w*2 + j)*6 + kc))*512);
    #pragma unroll
    for(int g=0;g<4;g++)
      #pragma unroll
      for(int j=0;j<2;j++){
        acc[0][g][j] = __builtin_amdgcn_mfma_f32_16x16x32_bf16(a0, b[g][j], acc[0][g][j],0,0,0);
        acc[1][g][j] = __builtin_amdgcn_mfma_f32_16x16x32_bf16(a1, b[g][j], acc[1][g][j],0,0,0);
      }
  }

  __syncthreads();   // all A reads (incl. h cols) complete before any h write below

  float bi[4][2];
  #pragma unroll
  for(int g=0;g<4;g++)
    #pragma unroll
    for(int j=0;j<2;j++)
      bi[g][j] = bias[g*128 + w*32 + j*16 + lm];

  #pragma unroll
  for(int mt=0;mt<2;mt++){
    #pragma unroll
    for(int q=0;q<4;q++){
      unsigned char mq = (q==0)?mk[mt].x:(q==1)?mk[mt].y:(q==2)?mk[mt].z:mk[mt].w;
      if(!mq) continue;
      int p = P0 + mt*16 + lq*4 + q;
      const float* cb = contrib + (long long)sg[mt][q]*512;
      float* crow = c_st + (long long)p*128;
      bf16* hrow = (bf16*)Apk + (long long)p*KP + 42;
      #pragma unroll
      for(int j=0;j<2;j++){
        int d = w*32 + j*16 + lm;
        float gi = acc[mt][0][j][q] + bi[0][j] + cb[      d];
        float gf = acc[mt][1][j][q] + bi[1][j] + cb[128 + d];
        float gg = acc[mt][2][j][q] + bi[2][j] + cb[256 + d];
        float go = acc[mt][3][j][q] + bi[3][j] + cb[384 + d];
        float co = crow[d];
        float cn = sigm(gf)*co + sigm(gi)*tanh_f(gg);
        float hn = sigm(go)*tanh_f(cn);
        crow[d] = cn;
        hrow[d] = __float2bfloat16(hn);
      }
    }
  }
}

// ---------- per-step epilogue: out head, rel/pos, alpha softmax, fields->dtp, traj ----------
__global__ void s3_post(const short* __restrict__ Apk_c, short* __restrict__ Apk,
                        float* __restrict__ rel, float* __restrict__ pos, float* __restrict__ al,
                        const void* __restrict__ Wout, const void* __restrict__ bout,
                        const void* __restrict__ fieldA, const void* __restrict__ trans,
                        const int* __restrict__ flags,
                        const unsigned char* __restrict__ mask, void* __restrict__ traj, int t){
  int grp = threadIdx.x>>6, lane = threadIdx.x&63;
  int p = blockIdx.x*4+grp;
  bool bf = flags[0]!=0;
  const bf16* hrow = (const bf16*)Apk_c + (long long)p*KP + 42;
  float h0 = b2f(hrow[lane]), h1 = b2f(hrow[64+lane]);
  float o0 = h0*ldf(Wout,lane*2,bf)   + h1*ldf(Wout,(64+lane)*2,bf);
  float o1 = h0*ldf(Wout,lane*2+1,bf) + h1*ldf(Wout,(64+lane)*2+1,bf);
  for(int m=1;m<64;m<<=1){ o0 += __shfl_xor(o0,m); o1 += __shfl_xor(o1,m); }
  o0 += ldf(bout,0,bf); o1 += ldf(bout,1,bf);
  bool msk = mask[p]!=0;
  float r0 = rel[p*2], r1 = rel[p*2+1];
  if(msk){ r0=o0; r1=o1; }
  float pn0 = pos[p*2]+r0, pn1 = pos[p*2+1]+r1;
  float a_l = (lane<NKK)? al[(long long)p*NKK+lane] : 0.f;
  float ad = -INFINITY;
  if(lane<NKK){
    float a2=0.f;
    #pragma unroll
    for(int i=0;i<NKK;i++) a2 += __shfl(a_l,i)*ldf(trans,i*NKK+lane,bf);
    ad = a2;
  }
  float mx = ad;
  for(int m=1;m<64;m<<=1) mx = fmaxf(mx, __shfl_xor(mx,m));
  float e = (lane<NKK)? __expf(ad-mx) : 0.f;
  float se = e;
  for(int m=1;m<64;m<<=1) se += __shfl_xor(se,m);
  float alp = e/se;
  if(msk && lane<NKK) al[(long long)p*NKK+lane] = alp;
  float alq = __shfl(alp, lane>>1);
  if(msk && lane<2*NKK){
    int kk=lane>>1, ee=lane&1;
    float fp = pn0*ldf(fieldA,kk*4+ee,bf) + pn1*ldf(fieldA,kk*4+2+ee,bf);
    ((bf16*)Apk)[(long long)p*KP+2+lane] = __float2bfloat16(fp*alq);
  }
  if(lane==0){
    if(msk){
      ((bf16*)Apk)[(long long)p*KP+0] = __float2bfloat16(r0);
      ((bf16*)Apk)[(long long)p*KP+1] = __float2bfloat16(r1);
    }
    rel[p*2]=r0; rel[p*2+1]=r1;
    pos[p*2]=pn0; pos[p*2+1]=pn1;
    long long base = (long long)t*N_PTS*2 + (long long)p*2;
    stf(traj, base,   r0, bf);
    stf(traj, base+1, r1, bf);
  }
}

extern "C" void kernel_launch(void* const* d_in, const int* in_sizes, int n_in,
                              void* d_out, int out_size, void* d_ws, size_t ws_size,
                              hipStream_t stream){
  const void* sf      = d_in[0];
  const void* lastpos = d_in[1];
  const void* alpha0  = d_in[2];
  const void* fd0     = d_in[3];
  const void* Wpos    = d_in[4];
  const void* bpos    = d_in[5];
  const void* Wfld    = d_in[6];
  const void* bfld    = d_in[7];
  const void* Wpool   = d_in[8];
  const void* bpool   = d_in[9];
  const void* Wx      = d_in[10];
  const void* Wh      = d_in[11];
  const void* blstm   = d_in[12];
  const void* Wout    = d_in[13];
  const void* bout    = d_in[14];
  const void* fieldA  = d_in[15];
  const void* trans   = d_in[16];
  const void* segids  = d_in[17];
  const unsigned char* maskraw = (const unsigned char*)d_in[18];

  char* ws = (char*)d_ws;
  size_t o = 0;
  auto alc = [&](size_t b){ size_t r=o; o=(o+b+255)&~(size_t)255; return r; };
  short* Apk       = (short*)(ws+alc((size_t)N_PTS*KP*2));
  float* c_st      = (float*)(ws+alc((size_t)N_PTS*128*4));
  float* rel       = (float*)(ws+alc((size_t)N_PTS*2*4));
  float* pos       = (float*)(ws+alc((size_t)N_PTS*2*4));
  float* al        = (float*)(ws+alc((size_t)N_PTS*20*4));
  int*   segst     = (int*)  (ws+alc((size_t)(NSEG+1)*4));
  short* segmax_bf = (short*)(ws+alc((size_t)NSEG*128*2));
  short* pool_bf   = (short*)(ws+alc((size_t)NSEG*128*2));
  float* contrib   = (float*)(ws+alc((size_t)NSEG*512*4));
  short* wTs       = (short*)(ws+alc((size_t)512*KP*2));
  float* bias      = (float*)(ws+alc((size_t)512*4));
  short* wpoolT    = (short*)(ws+alc((size_t)128*128*2));
  short* wxT2      = (short*)(ws+alc((size_t)512*128*2));
  unsigned char* mask = (unsigned char*)(ws+alc((size_t)N_PTS));
  int*   flags     = (int*)  (ws+alc(64));

  k_probe<<<1,64,0,stream>>>((const unsigned short*)Wx, (const int*)segids, maskraw, flags);
  k_conv<<<512,256,0,stream>>>(maskraw, flags, mask);
  k_segstart<<<33,256,0,stream>>>(segids, flags, segst);
  k_fold<<<706,256,0,stream>>>(Wpos,bpos,Wfld,bfld,Wx,Wh,blstm,flags,wTs,bias,wpoolT,Wpool,wxT2);
  k_init<<<32768,256,0,stream>>>(sf,lastpos,alpha0,fd0,Wout,bout,flags,Apk,c_st,rel,pos,al,d_out);

  for(int t=1;t<PRED;t++){
    s1a_segmax<<<NSEG,128,0,stream>>>(Apk, segst, segmax_bf);
    s1p_pool<<<NSEG/32,512,0,stream>>>(segmax_bf, wpoolT, bpool, flags, pool_bf);
    s1c_mfma<<<NSEG/32,512,0,stream>>>(pool_bf, wxT2, contrib);
    s2_mfma<<<N_PTS/32,256,0,stream>>>(Apk, c_st, wTs, bias, contrib, segids, flags, mask);
    s3_post<<<N_PTS/4,256,0,stream>>>(Apk, Apk, rel, pos, al, Wout, bout, fieldA, trans, flags, mask, d_out, t);
  }
}